// Round 1
// baseline (446.080 us; speedup 1.0000x reference)
//
#include <hip/hip_runtime.h>
#include <cstdint>
#include <cmath>

#define THREADS 256

// out[col] += sum_{r in [r0,r1)} (WEIGHTED ? w[r] : 1) * A[r][col]
// Each thread handles 4 consecutive columns (float4), blocks tile rows.
template <bool WEIGHTED>
__global__ void colsum_kernel(const float* __restrict__ A,
                              const float* __restrict__ w,
                              float* __restrict__ out,
                              int N, int rowsPerBlock) {
    int col = blockIdx.x * (THREADS * 4) + threadIdx.x * 4;
    if (col >= N) return;
    int r0 = blockIdx.y * rowsPerBlock;
    int r1 = r0 + rowsPerBlock;
    if (r1 > N) r1 = N;
    float ax = 0.f, ay = 0.f, az = 0.f, aw = 0.f;
    const float* p = A + (size_t)r0 * N + col;
    for (int r = r0; r < r1; ++r, p += N) {
        float4 v = *reinterpret_cast<const float4*>(p);
        float wr = WEIGHTED ? w[r] : 1.0f;
        ax += wr * v.x;
        ay += wr * v.y;
        az += wr * v.z;
        aw += wr * v.w;
    }
    atomicAdd(&out[col + 0], ax);
    atomicAdd(&out[col + 1], ay);
    atomicAdd(&out[col + 2], az);
    atomicAdd(&out[col + 3], aw);
}

// For feat [N][L] (L = 1<<log2L), computes:
//   out[0..L)    += colsum(feat)            (s)
//   out[L..2L)   += sum_r c[r]*feat[r,:]    (p)
//   out[2L..3L)  += sum_r d[r]*feat[r,:]    (q, only if HAS_Q)
template <bool HAS_Q>
__global__ void feat_reduce_kernel(const float* __restrict__ feat,
                                   const float* __restrict__ c,
                                   const float* __restrict__ d,
                                   float* __restrict__ out,
                                   int total, int log2L) {
    int stride = gridDim.x * blockDim.x;   // must be multiple of L
    int idx = blockIdx.x * blockDim.x + threadIdx.x;
    int L = 1 << log2L;
    int l = idx & (L - 1);                 // constant per thread
    float as = 0.f, ap = 0.f, aq = 0.f;
    for (int i = idx; i < total; i += stride) {
        float v = feat[i];
        int r = i >> log2L;
        as += v;
        ap += c[r] * v;
        if (HAS_Q) aq += d[r] * v;
    }
    atomicAdd(&out[l], as);
    atomicAdd(&out[L + l], ap);
    if (HAS_Q) atomicAdd(&out[2 * L + l], aq);
}

// scoring[b][k] = sum_{d,e} e1[d] * W[d,e,k] * e2[e]
// grid = (16 chunks, 4 branches); W read linearly (coalesced), k = idx & 15.
__global__ void scoring_kernel(const float* __restrict__ Wn,
                               const float* __restrict__ We,
                               const float* __restrict__ n1,
                               const float* __restrict__ n2,
                               const float* __restrict__ eg1,
                               const float* __restrict__ eg2,
                               float* __restrict__ scoring) {
    int b = blockIdx.y;
    int chunk = blockIdx.x;
    const float *W, *e1, *e2;
    int total, log2D;
    if (b < 3) {
        W = Wn + (size_t)b * (64 * 64 * 16);
        e1 = n1 + (b == 2 ? 32 : 0);   // b0,b1: g_01 ; b2: g_12
        e2 = n2 + (b == 2 ? 32 : 0);
        total = 64 * 64 * 16;
        log2D = 6;
    } else {
        W = We;
        e1 = eg1;
        e2 = eg2;
        total = 32 * 32 * 16;
        log2D = 5;
    }
    int begin = chunk * 4096 + threadIdx.x;
    int end = (chunk + 1) * 4096;
    if (end > total) end = total;
    float acc = 0.f;
    for (int idx = begin; idx < end; idx += 256) {
        int de = idx >> 4;
        int e = de & ((1 << log2D) - 1);
        int dd = de >> log2D;
        acc += e1[dd] * e2[e] * W[idx];
    }
    __shared__ float red[256];
    red[threadIdx.x] = acc;
    __syncthreads();
    if (threadIdx.x < 16) {
        float s = 0.f;
        for (int t = threadIdx.x; t < 256; t += 16) s += red[t];
        atomicAdd(&scoring[b * 16 + threadIdx.x], s);
    }
}

// One block, 64 threads: block-term + relu -> MLPs -> sigmoid -> outputs.
__global__ void final_kernel(const float* __restrict__ scoring,
                             const float* __restrict__ n1,
                             const float* __restrict__ n2,
                             const float* __restrict__ eg1,
                             const float* __restrict__ eg2,
                             const float* __restrict__ Wbn,
                             const float* __restrict__ bn,
                             const float* __restrict__ Wbe,
                             const float* __restrict__ be,
                             const float* __restrict__ m1w,
                             const float* __restrict__ m1b,
                             const float* __restrict__ m2w,
                             const float* __restrict__ m2b,
                             const float* __restrict__ m3w,
                             const float* __restrict__ m3b,
                             const float* __restrict__ sw,
                             const float* __restrict__ sb,
                             const float* __restrict__ avg_v,
                             float* __restrict__ out) {
    __shared__ float sval[4][16];
    __shared__ float scores[4];
    int t = threadIdx.x;          // 64 threads
    int b = t >> 4, k = t & 15;

    float blk;
    if (b < 3) {
        const float* e1 = n1 + (b == 2 ? 32 : 0);
        const float* e2 = n2 + (b == 2 ? 32 : 0);
        const float* wb = Wbn + (size_t)b * (16 * 128) + k * 128;
        float s = 0.f;
        for (int j = 0; j < 64; ++j) s += wb[j] * e1[j];
        for (int j = 0; j < 64; ++j) s += wb[64 + j] * e2[j];
        blk = s + bn[b * 16 + k];
    } else {
        const float* wb = Wbe + k * 64;
        float s = 0.f;
        for (int j = 0; j < 32; ++j) s += wb[j] * eg1[j];
        for (int j = 0; j < 32; ++j) s += wb[32 + j] * eg2[j];
        blk = s + be[k];
    }
    float v = scoring[b * 16 + k] + blk;
    sval[b][k] = v > 0.f ? v : 0.f;
    __syncthreads();

    if (t < 4) {
        float h1[16], h2[8], h3[4];
        for (int o = 0; o < 16; ++o) {
            float a = m1b[t * 16 + o];
            for (int i = 0; i < 16; ++i) a += m1w[(t * 16 + o) * 16 + i] * sval[t][i];
            h1[o] = a > 0.f ? a : 0.f;
        }
        for (int o = 0; o < 8; ++o) {
            float a = m2b[t * 8 + o];
            for (int i = 0; i < 16; ++i) a += m2w[(t * 8 + o) * 16 + i] * h1[i];
            h2[o] = a > 0.f ? a : 0.f;
        }
        for (int o = 0; o < 4; ++o) {
            float a = m3b[t * 4 + o];
            for (int i = 0; i < 8; ++i) a += m3w[(t * 4 + o) * 8 + i] * h2[i];
            h3[o] = a > 0.f ? a : 0.f;
        }
        float z = sb[t];
        for (int i = 0; i < 4; ++i) z += sw[t * 4 + i] * h3[i];
        scores[t] = 1.0f / (1.0f + expf(-z));
    }
    __syncthreads();

    if (t == 0) {
        const int ord[4] = {0, 1, 3, 2};   // (nc, in, ec, ie)
        float av = avg_v[0];
        float acc = 0.f;
        for (int j = 0; j < 4; ++j) {
            float sc = scores[ord[j]];
            out[2 + j] = sc;
            acc += -logf(sc);
        }
        float ged = acc * av;
        out[1] = ged;
        out[0] = expf(-ged / av);
    }
}

extern "C" void kernel_launch(void* const* d_in, const int* in_sizes, int n_in,
                              void* d_out, int out_size, void* d_ws, size_t ws_size,
                              hipStream_t stream) {
    const float* emb1  = (const float*)d_in[0];
    const float* emb2  = (const float*)d_in[1];
    const float* adj1  = (const float*)d_in[2];
    const float* adj2  = (const float*)d_in[3];
    const float* eat1  = (const float*)d_in[4];
    const float* eat2  = (const float*)d_in[5];
    const float* eadj1 = (const float*)d_in[6];
    const float* eadj2 = (const float*)d_in[7];
    const float* avg_v = (const float*)d_in[8];
    const float* Wn    = (const float*)d_in[9];
    const float* Wbn   = (const float*)d_in[10];
    const float* bn    = (const float*)d_in[11];
    const float* We    = (const float*)d_in[12];
    const float* Wbe   = (const float*)d_in[13];
    const float* be    = (const float*)d_in[14];
    const float* m1w   = (const float*)d_in[15];
    const float* m1b   = (const float*)d_in[16];
    const float* m2w   = (const float*)d_in[17];
    const float* m2b   = (const float*)d_in[18];
    const float* m3w   = (const float*)d_in[19];
    const float* m3b   = (const float*)d_in[20];
    const float* sw    = (const float*)d_in[21];
    const float* sb    = (const float*)d_in[22];

    int Nn = in_sizes[0] / 32;   // 6000 nodes
    int Ne = in_sizes[4] / 16;   // 6000 edges

    float* ws  = (float*)d_ws;
    float* c1  = ws;
    float* d1  = c1 + Nn;
    float* c2  = d1 + Nn;
    float* d2  = c2 + Nn;
    float* ce1 = d2 + Nn;
    float* ce2 = ce1 + Ne;
    float* n1  = ce2 + Ne;     // [s_emb1(32), p1(32), q1(32)]
    float* n2  = n1 + 96;
    float* eg1 = n2 + 96;      // [se1(16), pe1(16)]
    float* eg2 = eg1 + 32;
    float* scoring = eg2 + 32; // [4][16]
    size_t totalFloats = (size_t)((scoring + 64) - ws);
    hipMemsetAsync(d_ws, 0, totalFloats * sizeof(float), stream);

    const int ROWS = 32;
    dim3 blk(THREADS);
    dim3 gridN((Nn + THREADS * 4 - 1) / (THREADS * 4), (Nn + ROWS - 1) / ROWS);
    dim3 gridE((Ne + THREADS * 4 - 1) / (THREADS * 4), (Ne + ROWS - 1) / ROWS);

    // Order c,d back-to-back per matrix so the d-pass re-reads from L3 (144MB < 256MB).
    colsum_kernel<false><<<gridN, blk, 0, stream>>>(adj1, nullptr, c1, Nn, ROWS);
    colsum_kernel<true ><<<gridN, blk, 0, stream>>>(adj1, c1,      d1, Nn, ROWS);
    colsum_kernel<false><<<gridN, blk, 0, stream>>>(adj2, nullptr, c2, Nn, ROWS);
    colsum_kernel<true ><<<gridN, blk, 0, stream>>>(adj2, c2,      d2, Nn, ROWS);
    colsum_kernel<false><<<gridE, blk, 0, stream>>>(eadj1, nullptr, ce1, Ne, ROWS);
    colsum_kernel<false><<<gridE, blk, 0, stream>>>(eadj2, nullptr, ce2, Ne, ROWS);

    feat_reduce_kernel<true ><<<64, 256, 0, stream>>>(emb1, c1, d1, n1, Nn * 32, 5);
    feat_reduce_kernel<true ><<<64, 256, 0, stream>>>(emb2, c2, d2, n2, Nn * 32, 5);
    feat_reduce_kernel<false><<<64, 256, 0, stream>>>(eat1, ce1, nullptr, eg1, Ne * 16, 4);
    feat_reduce_kernel<false><<<64, 256, 0, stream>>>(eat2, ce2, nullptr, eg2, Ne * 16, 4);

    scoring_kernel<<<dim3(16, 4), 256, 0, stream>>>(Wn, We, n1, n2, eg1, eg2, scoring);

    final_kernel<<<1, 64, 0, stream>>>(scoring, n1, n2, eg1, eg2,
                                       Wbn, bn, Wbe, be,
                                       m1w, m1b, m2w, m2b, m3w, m3b, sw, sb,
                                       avg_v, (float*)d_out);
}

// Round 2
// 324.377 us; speedup vs baseline: 1.3752x; 1.3752x over previous
//
#include <hip/hip_runtime.h>
#include <cstdint>
#include <cmath>

#define THREADS 256
#define ROWS_PER_BLK 32
#define LDP 6016   // padded leading dim for partials (multiple of 4)

// Stage 1: partial column sums, NO atomics.
// P[blockIdx.y][col] = sum_{r in [r0,r1)} (W ? w[r] : 1) * A[r][col]
template <bool WEIGHTED>
__global__ void colsum_part_kernel(const float* __restrict__ A,
                                   const float* __restrict__ w,
                                   float* __restrict__ P,
                                   int N) {
    int col = blockIdx.x * (THREADS * 4) + threadIdx.x * 4;
    if (col >= N) return;
    int r0 = blockIdx.y * ROWS_PER_BLK;
    int r1 = r0 + ROWS_PER_BLK;
    if (r1 > N) r1 = N;
    float ax = 0.f, ay = 0.f, az = 0.f, aw = 0.f;
    const float* p = A + (size_t)r0 * N + col;
#pragma unroll 4
    for (int r = r0; r < r1; ++r, p += N) {
        float4 v = *reinterpret_cast<const float4*>(p);
        float wr = WEIGHTED ? w[r] : 1.0f;
        ax += wr * v.x;
        ay += wr * v.y;
        az += wr * v.z;
        aw += wr * v.w;
    }
    float4 o = {ax, ay, az, aw};
    *reinterpret_cast<float4*>(&P[(size_t)blockIdx.y * LDP + col]) = o;
}

// Stage 2: out[col] = sum_i P[i][col]. Coalesced, atomic-free.
__global__ void reduce_part_kernel(const float* __restrict__ P,
                                   float* __restrict__ out,
                                   int N, int nParts) {
    int col = blockIdx.x * THREADS + threadIdx.x;
    if (col >= N) return;
    float s = 0.f;
    const float* p = P + col;
#pragma unroll 4
    for (int i = 0; i < nParts; ++i, p += LDP) s += *p;
    out[col] = s;
}

// Merged feature reductions for all 4 branches.
// unit 0: emb1 (L=32, c1,d1 -> n1[96])   unit 1: emb2 -> n2
// unit 2: eat1 (L=16, ce1  -> eg1[32])   unit 3: eat2 -> eg2
__global__ void feat_all_kernel(const float* __restrict__ emb1,
                                const float* __restrict__ emb2,
                                const float* __restrict__ eat1,
                                const float* __restrict__ eat2,
                                const float* __restrict__ c1,
                                const float* __restrict__ d1,
                                const float* __restrict__ c2,
                                const float* __restrict__ d2,
                                const float* __restrict__ ce1,
                                const float* __restrict__ ce2,
                                float* __restrict__ n1,
                                float* __restrict__ n2,
                                float* __restrict__ eg1,
                                float* __restrict__ eg2,
                                int Nn, int Ne) {
    int unit = blockIdx.y;
    const float *feat, *c, *d;
    float* out;
    int total, log2L;
    bool hasQ;
    if (unit == 0)      { feat = emb1; c = c1;  d = d1;      out = n1;  total = Nn * 32; log2L = 5; hasQ = true;  }
    else if (unit == 1) { feat = emb2; c = c2;  d = d2;      out = n2;  total = Nn * 32; log2L = 5; hasQ = true;  }
    else if (unit == 2) { feat = eat1; c = ce1; d = nullptr; out = eg1; total = Ne * 16; log2L = 4; hasQ = false; }
    else                { feat = eat2; c = ce2; d = nullptr; out = eg2; total = Ne * 16; log2L = 4; hasQ = false; }

    int stride = gridDim.x * blockDim.x;   // 4096, multiple of L
    int idx = blockIdx.x * blockDim.x + threadIdx.x;
    int L = 1 << log2L;
    int l = idx & (L - 1);
    float as = 0.f, ap = 0.f, aq = 0.f;
    for (int i = idx; i < total; i += stride) {
        float v = feat[i];
        int r = i >> log2L;
        as += v;
        ap += c[r] * v;
        if (hasQ) aq += d[r] * v;
    }
    atomicAdd(&out[l], as);
    atomicAdd(&out[L + l], ap);
    if (hasQ) atomicAdd(&out[2 * L + l], aq);
}

// scoring[b][k] = sum_{d,e} e1[d] * W[d,e,k] * e2[e]
__global__ void scoring_kernel(const float* __restrict__ Wn,
                               const float* __restrict__ We,
                               const float* __restrict__ n1,
                               const float* __restrict__ n2,
                               const float* __restrict__ eg1,
                               const float* __restrict__ eg2,
                               float* __restrict__ scoring) {
    int b = blockIdx.y;
    int chunk = blockIdx.x;
    const float *W, *e1, *e2;
    int total, log2D;
    if (b < 3) {
        W = Wn + (size_t)b * (64 * 64 * 16);
        e1 = n1 + (b == 2 ? 32 : 0);   // b0,b1: g_01 ; b2: g_12
        e2 = n2 + (b == 2 ? 32 : 0);
        total = 64 * 64 * 16;
        log2D = 6;
    } else {
        W = We;
        e1 = eg1;
        e2 = eg2;
        total = 32 * 32 * 16;
        log2D = 5;
    }
    int begin = chunk * 4096 + threadIdx.x;
    int end = (chunk + 1) * 4096;
    if (end > total) end = total;
    float acc = 0.f;
    for (int idx = begin; idx < end; idx += 256) {
        int de = idx >> 4;
        int e = de & ((1 << log2D) - 1);
        int dd = de >> log2D;
        acc += e1[dd] * e2[e] * W[idx];
    }
    __shared__ float red[256];
    red[threadIdx.x] = acc;
    __syncthreads();
    if (threadIdx.x < 16) {
        float s = 0.f;
        for (int t = threadIdx.x; t < 256; t += 16) s += red[t];
        atomicAdd(&scoring[b * 16 + threadIdx.x], s);
    }
}

// One block, 64 threads: block-term + relu -> MLPs -> sigmoid -> outputs.
__global__ void final_kernel(const float* __restrict__ scoring,
                             const float* __restrict__ n1,
                             const float* __restrict__ n2,
                             const float* __restrict__ eg1,
                             const float* __restrict__ eg2,
                             const float* __restrict__ Wbn,
                             const float* __restrict__ bn,
                             const float* __restrict__ Wbe,
                             const float* __restrict__ be,
                             const float* __restrict__ m1w,
                             const float* __restrict__ m1b,
                             const float* __restrict__ m2w,
                             const float* __restrict__ m2b,
                             const float* __restrict__ m3w,
                             const float* __restrict__ m3b,
                             const float* __restrict__ sw,
                             const float* __restrict__ sb,
                             const float* __restrict__ avg_v,
                             float* __restrict__ out) {
    __shared__ float sval[4][16];
    __shared__ float scores[4];
    int t = threadIdx.x;          // 64 threads
    int b = t >> 4, k = t & 15;

    float blk;
    if (b < 3) {
        const float* e1 = n1 + (b == 2 ? 32 : 0);
        const float* e2 = n2 + (b == 2 ? 32 : 0);
        const float* wb = Wbn + (size_t)b * (16 * 128) + k * 128;
        float s = 0.f;
        for (int j = 0; j < 64; ++j) s += wb[j] * e1[j];
        for (int j = 0; j < 64; ++j) s += wb[64 + j] * e2[j];
        blk = s + bn[b * 16 + k];
    } else {
        const float* wb = Wbe + k * 64;
        float s = 0.f;
        for (int j = 0; j < 32; ++j) s += wb[j] * eg1[j];
        for (int j = 0; j < 32; ++j) s += wb[32 + j] * eg2[j];
        blk = s + be[k];
    }
    float v = scoring[b * 16 + k] + blk;
    sval[b][k] = v > 0.f ? v : 0.f;
    __syncthreads();

    if (t < 4) {
        float h1[16], h2[8], h3[4];
        for (int o = 0; o < 16; ++o) {
            float a = m1b[t * 16 + o];
            for (int i = 0; i < 16; ++i) a += m1w[(t * 16 + o) * 16 + i] * sval[t][i];
            h1[o] = a > 0.f ? a : 0.f;
        }
        for (int o = 0; o < 8; ++o) {
            float a = m2b[t * 8 + o];
            for (int i = 0; i < 16; ++i) a += m2w[(t * 8 + o) * 16 + i] * h1[i];
            h2[o] = a > 0.f ? a : 0.f;
        }
        for (int o = 0; o < 4; ++o) {
            float a = m3b[t * 4 + o];
            for (int i = 0; i < 8; ++i) a += m3w[(t * 4 + o) * 8 + i] * h2[i];
            h3[o] = a > 0.f ? a : 0.f;
        }
        float z = sb[t];
        for (int i = 0; i < 4; ++i) z += sw[t * 4 + i] * h3[i];
        scores[t] = 1.0f / (1.0f + expf(-z));
    }
    __syncthreads();

    if (t == 0) {
        const int ord[4] = {0, 1, 3, 2};   // (nc, in, ec, ie)
        float av = avg_v[0];
        float acc = 0.f;
        for (int j = 0; j < 4; ++j) {
            float sc = scores[ord[j]];
            out[2 + j] = sc;
            acc += -logf(sc);
        }
        float ged = acc * av;
        out[1] = ged;
        out[0] = expf(-ged / av);
    }
}

extern "C" void kernel_launch(void* const* d_in, const int* in_sizes, int n_in,
                              void* d_out, int out_size, void* d_ws, size_t ws_size,
                              hipStream_t stream) {
    const float* emb1  = (const float*)d_in[0];
    const float* emb2  = (const float*)d_in[1];
    const float* adj1  = (const float*)d_in[2];
    const float* adj2  = (const float*)d_in[3];
    const float* eat1  = (const float*)d_in[4];
    const float* eat2  = (const float*)d_in[5];
    const float* eadj1 = (const float*)d_in[6];
    const float* eadj2 = (const float*)d_in[7];
    const float* avg_v = (const float*)d_in[8];
    const float* Wn    = (const float*)d_in[9];
    const float* Wbn   = (const float*)d_in[10];
    const float* bn    = (const float*)d_in[11];
    const float* We    = (const float*)d_in[12];
    const float* Wbe   = (const float*)d_in[13];
    const float* be    = (const float*)d_in[14];
    const float* m1w   = (const float*)d_in[15];
    const float* m1b   = (const float*)d_in[16];
    const float* m2w   = (const float*)d_in[17];
    const float* m2b   = (const float*)d_in[18];
    const float* m3w   = (const float*)d_in[19];
    const float* m3b   = (const float*)d_in[20];
    const float* sw    = (const float*)d_in[21];
    const float* sb    = (const float*)d_in[22];

    int Nn = in_sizes[0] / 32;   // 6000 nodes
    int Ne = in_sizes[4] / 16;   // 6000 edges
    int nPartsN = (Nn + ROWS_PER_BLK - 1) / ROWS_PER_BLK;   // 188
    int nPartsE = (Ne + ROWS_PER_BLK - 1) / ROWS_PER_BLK;

    float* ws  = (float*)d_ws;
    float* P   = ws;                       // [nParts][LDP] partials, reused
    float* c1  = P + (size_t)nPartsN * LDP;
    float* d1  = c1 + Nn;
    float* c2  = d1 + Nn;
    float* d2  = c2 + Nn;
    float* ce1 = d2 + Nn;
    float* ce2 = ce1 + Ne;
    float* n1  = ce2 + Ne;     // [s(32), p(32), q(32)]
    float* n2  = n1 + 96;
    float* eg1 = n2 + 96;      // [s(16), p(16)]
    float* eg2 = eg1 + 32;
    float* scoring = eg2 + 32; // [4][16]
    // zero only the atomically-accumulated tail: n1..scoring = 96*2+32*2+64 = 320 floats
    hipMemsetAsync(n1, 0, 320 * sizeof(float), stream);

    dim3 blk(THREADS);
    dim3 gridN((Nn + THREADS * 4 - 1) / (THREADS * 4), nPartsN);
    dim3 gridE((Ne + THREADS * 4 - 1) / (THREADS * 4), nPartsE);
    dim3 gridR((Nn + THREADS - 1) / THREADS);   // 24 blocks

    // adj1: c then (L3-resident) weighted d
    colsum_part_kernel<false><<<gridN, blk, 0, stream>>>(adj1, nullptr, P, Nn);
    reduce_part_kernel<<<gridR, blk, 0, stream>>>(P, c1, Nn, nPartsN);
    colsum_part_kernel<true ><<<gridN, blk, 0, stream>>>(adj1, c1, P, Nn);
    reduce_part_kernel<<<gridR, blk, 0, stream>>>(P, d1, Nn, nPartsN);
    // adj2
    colsum_part_kernel<false><<<gridN, blk, 0, stream>>>(adj2, nullptr, P, Nn);
    reduce_part_kernel<<<gridR, blk, 0, stream>>>(P, c2, Nn, nPartsN);
    colsum_part_kernel<true ><<<gridN, blk, 0, stream>>>(adj2, c2, P, Nn);
    reduce_part_kernel<<<gridR, blk, 0, stream>>>(P, d2, Nn, nPartsN);
    // edge adjacencies: single unweighted pass each
    colsum_part_kernel<false><<<gridE, blk, 0, stream>>>(eadj1, nullptr, P, Ne);
    reduce_part_kernel<<<gridR, blk, 0, stream>>>(P, ce1, Ne, nPartsE);
    colsum_part_kernel<false><<<gridE, blk, 0, stream>>>(eadj2, nullptr, P, Ne);
    reduce_part_kernel<<<gridR, blk, 0, stream>>>(P, ce2, Ne, nPartsE);

    feat_all_kernel<<<dim3(16, 4), blk, 0, stream>>>(emb1, emb2, eat1, eat2,
                                                     c1, d1, c2, d2, ce1, ce2,
                                                     n1, n2, eg1, eg2, Nn, Ne);

    scoring_kernel<<<dim3(16, 4), blk, 0, stream>>>(Wn, We, n1, n2, eg1, eg2, scoring);

    final_kernel<<<1, 64, 0, stream>>>(scoring, n1, n2, eg1, eg2,
                                       Wbn, bn, Wbe, be,
                                       m1w, m1b, m2w, m2b, m3w, m3b, sw, sb,
                                       avg_v, (float*)d_out);
}

// Round 3
// 256.621 us; speedup vs baseline: 1.7383x; 1.2640x over previous
//
#include <hip/hip_runtime.h>
#include <cstdint>
#include <cmath>

#define THREADS 256
#define ROWS_PER_BLK 64
#define LDP 6016   // padded leading dim for partials (multiple of 4)

// Fused partial column sums for TWO matrices (blockIdx.z selects), NO atomics.
// P[z][blockIdx.y][col] = sum_{r in strip} (W ? w[r] : 1) * A[r][col]
template <bool WEIGHTED>
__global__ void colsum2_kernel(const float* __restrict__ A0,
                               const float* __restrict__ A1,
                               const float* __restrict__ w0,
                               const float* __restrict__ w1,
                               float* __restrict__ P,
                               int N, int nParts) {
    const float* A = blockIdx.z ? A1 : A0;
    const float* w = blockIdx.z ? w1 : w0;
    float* Pm = P + (size_t)blockIdx.z * nParts * LDP;

    int col = blockIdx.x * (THREADS * 4) + threadIdx.x * 4;
    if (col >= N) return;
    int r0 = blockIdx.y * ROWS_PER_BLK;
    int r1 = r0 + ROWS_PER_BLK;
    if (r1 > N) r1 = N;
    float ax = 0.f, ay = 0.f, az = 0.f, aw = 0.f;
    const float* p = A + (size_t)r0 * N + col;
#pragma unroll 4
    for (int r = r0; r < r1; ++r, p += N) {
        float4 v = *reinterpret_cast<const float4*>(p);
        float wr = WEIGHTED ? w[r] : 1.0f;
        ax += wr * v.x;
        ay += wr * v.y;
        az += wr * v.z;
        aw += wr * v.w;
    }
    float4 o = {ax, ay, az, aw};
    *reinterpret_cast<float4*>(&Pm[(size_t)blockIdx.y * LDP + col]) = o;
}

// Fused stage-2 for two outputs: out_z[col] = sum_i P[z][i][col].
__global__ void reduce2_kernel(const float* __restrict__ P,
                               float* __restrict__ out0,
                               float* __restrict__ out1,
                               int N, int nParts) {
    int col = blockIdx.x * THREADS + threadIdx.x;
    if (col >= N) return;
    const float* p = P + (size_t)blockIdx.y * nParts * LDP + col;
    float* out = blockIdx.y ? out1 : out0;
    float s = 0.f;
#pragma unroll 4
    for (int i = 0; i < nParts; ++i, p += LDP) s += *p;
    out[col] = s;
}

// Merged feature reductions for all 4 branches.
// unit 0: emb1 (L=32, c1,d1 -> n1[96])   unit 1: emb2 -> n2
// unit 2: eat1 (L=16, ce1  -> eg1[32])   unit 3: eat2 -> eg2
__global__ void feat_all_kernel(const float* __restrict__ emb1,
                                const float* __restrict__ emb2,
                                const float* __restrict__ eat1,
                                const float* __restrict__ eat2,
                                const float* __restrict__ c1,
                                const float* __restrict__ d1,
                                const float* __restrict__ c2,
                                const float* __restrict__ d2,
                                const float* __restrict__ ce1,
                                const float* __restrict__ ce2,
                                float* __restrict__ n1,
                                float* __restrict__ n2,
                                float* __restrict__ eg1,
                                float* __restrict__ eg2,
                                int Nn, int Ne) {
    int unit = blockIdx.y;
    const float *feat, *c, *d;
    float* out;
    int total, log2L;
    bool hasQ;
    if (unit == 0)      { feat = emb1; c = c1;  d = d1;      out = n1;  total = Nn * 32; log2L = 5; hasQ = true;  }
    else if (unit == 1) { feat = emb2; c = c2;  d = d2;      out = n2;  total = Nn * 32; log2L = 5; hasQ = true;  }
    else if (unit == 2) { feat = eat1; c = ce1; d = nullptr; out = eg1; total = Ne * 16; log2L = 4; hasQ = false; }
    else                { feat = eat2; c = ce2; d = nullptr; out = eg2; total = Ne * 16; log2L = 4; hasQ = false; }

    int stride = gridDim.x * blockDim.x;   // multiple of L
    int idx = blockIdx.x * blockDim.x + threadIdx.x;
    int L = 1 << log2L;
    int l = idx & (L - 1);
    float as = 0.f, ap = 0.f, aq = 0.f;
    for (int i = idx; i < total; i += stride) {
        float v = feat[i];
        int r = i >> log2L;
        as += v;
        ap += c[r] * v;
        if (hasQ) aq += d[r] * v;
    }
    atomicAdd(&out[l], as);
    atomicAdd(&out[L + l], ap);
    if (hasQ) atomicAdd(&out[2 * L + l], aq);
}

// scoring[b][k] = sum_{d,e} e1[d] * W[d,e,k] * e2[e]
__global__ void scoring_kernel(const float* __restrict__ Wn,
                               const float* __restrict__ We,
                               const float* __restrict__ n1,
                               const float* __restrict__ n2,
                               const float* __restrict__ eg1,
                               const float* __restrict__ eg2,
                               float* __restrict__ scoring) {
    int b = blockIdx.y;
    int chunk = blockIdx.x;
    const float *W, *e1, *e2;
    int total, log2D;
    if (b < 3) {
        W = Wn + (size_t)b * (64 * 64 * 16);
        e1 = n1 + (b == 2 ? 32 : 0);   // b0,b1: g_01 ; b2: g_12
        e2 = n2 + (b == 2 ? 32 : 0);
        total = 64 * 64 * 16;
        log2D = 6;
    } else {
        W = We;
        e1 = eg1;
        e2 = eg2;
        total = 32 * 32 * 16;
        log2D = 5;
    }
    int begin = chunk * 4096 + threadIdx.x;
    int end = (chunk + 1) * 4096;
    if (end > total) end = total;
    float acc = 0.f;
    for (int idx = begin; idx < end; idx += 256) {
        int de = idx >> 4;
        int e = de & ((1 << log2D) - 1);
        int dd = de >> log2D;
        acc += e1[dd] * e2[e] * W[idx];
    }
    __shared__ float red[256];
    red[threadIdx.x] = acc;
    __syncthreads();
    if (threadIdx.x < 16) {
        float s = 0.f;
        for (int t = threadIdx.x; t < 256; t += 16) s += red[t];
        atomicAdd(&scoring[b * 16 + threadIdx.x], s);
    }
}

// One block, 64 threads: block-term + relu -> MLPs -> sigmoid -> outputs.
__global__ void final_kernel(const float* __restrict__ scoring,
                             const float* __restrict__ n1,
                             const float* __restrict__ n2,
                             const float* __restrict__ eg1,
                             const float* __restrict__ eg2,
                             const float* __restrict__ Wbn,
                             const float* __restrict__ bn,
                             const float* __restrict__ Wbe,
                             const float* __restrict__ be,
                             const float* __restrict__ m1w,
                             const float* __restrict__ m1b,
                             const float* __restrict__ m2w,
                             const float* __restrict__ m2b,
                             const float* __restrict__ m3w,
                             const float* __restrict__ m3b,
                             const float* __restrict__ sw,
                             const float* __restrict__ sb,
                             const float* __restrict__ avg_v,
                             float* __restrict__ out) {
    __shared__ float sval[4][16];
    __shared__ float scores[4];
    int t = threadIdx.x;          // 64 threads
    int b = t >> 4, k = t & 15;

    float blk;
    if (b < 3) {
        const float* e1 = n1 + (b == 2 ? 32 : 0);
        const float* e2 = n2 + (b == 2 ? 32 : 0);
        const float* wb = Wbn + (size_t)b * (16 * 128) + k * 128;
        float s = 0.f;
        for (int j = 0; j < 64; ++j) s += wb[j] * e1[j];
        for (int j = 0; j < 64; ++j) s += wb[64 + j] * e2[j];
        blk = s + bn[b * 16 + k];
    } else {
        const float* wb = Wbe + k * 64;
        float s = 0.f;
        for (int j = 0; j < 32; ++j) s += wb[j] * eg1[j];
        for (int j = 0; j < 32; ++j) s += wb[32 + j] * eg2[j];
        blk = s + be[k];
    }
    float v = scoring[b * 16 + k] + blk;
    sval[b][k] = v > 0.f ? v : 0.f;
    __syncthreads();

    if (t < 4) {
        float h1[16], h2[8], h3[4];
        for (int o = 0; o < 16; ++o) {
            float a = m1b[t * 16 + o];
            for (int i = 0; i < 16; ++i) a += m1w[(t * 16 + o) * 16 + i] * sval[t][i];
            h1[o] = a > 0.f ? a : 0.f;
        }
        for (int o = 0; o < 8; ++o) {
            float a = m2b[t * 8 + o];
            for (int i = 0; i < 16; ++i) a += m2w[(t * 8 + o) * 16 + i] * h1[i];
            h2[o] = a > 0.f ? a : 0.f;
        }
        for (int o = 0; o < 4; ++o) {
            float a = m3b[t * 4 + o];
            for (int i = 0; i < 8; ++i) a += m3w[(t * 4 + o) * 8 + i] * h2[i];
            h3[o] = a > 0.f ? a : 0.f;
        }
        float z = sb[t];
        for (int i = 0; i < 4; ++i) z += sw[t * 4 + i] * h3[i];
        scores[t] = 1.0f / (1.0f + expf(-z));
    }
    __syncthreads();

    if (t == 0) {
        const int ord[4] = {0, 1, 3, 2};   // (nc, in, ec, ie)
        float av = avg_v[0];
        float acc = 0.f;
        for (int j = 0; j < 4; ++j) {
            float sc = scores[ord[j]];
            out[2 + j] = sc;
            acc += -logf(sc);
        }
        float ged = acc * av;
        out[1] = ged;
        out[0] = expf(-ged / av);
    }
}

extern "C" void kernel_launch(void* const* d_in, const int* in_sizes, int n_in,
                              void* d_out, int out_size, void* d_ws, size_t ws_size,
                              hipStream_t stream) {
    const float* emb1  = (const float*)d_in[0];
    const float* emb2  = (const float*)d_in[1];
    const float* adj1  = (const float*)d_in[2];
    const float* adj2  = (const float*)d_in[3];
    const float* eat1  = (const float*)d_in[4];
    const float* eat2  = (const float*)d_in[5];
    const float* eadj1 = (const float*)d_in[6];
    const float* eadj2 = (const float*)d_in[7];
    const float* avg_v = (const float*)d_in[8];
    const float* Wn    = (const float*)d_in[9];
    const float* Wbn   = (const float*)d_in[10];
    const float* bn    = (const float*)d_in[11];
    const float* We    = (const float*)d_in[12];
    const float* Wbe   = (const float*)d_in[13];
    const float* be    = (const float*)d_in[14];
    const float* m1w   = (const float*)d_in[15];
    const float* m1b   = (const float*)d_in[16];
    const float* m2w   = (const float*)d_in[17];
    const float* m2b   = (const float*)d_in[18];
    const float* m3w   = (const float*)d_in[19];
    const float* m3b   = (const float*)d_in[20];
    const float* sw    = (const float*)d_in[21];
    const float* sb    = (const float*)d_in[22];

    int Nn = in_sizes[0] / 32;   // 6000 nodes
    int Ne = in_sizes[4] / 16;   // 6000 edges
    int nPartsN = (Nn + ROWS_PER_BLK - 1) / ROWS_PER_BLK;   // 94
    int nPartsE = (Ne + ROWS_PER_BLK - 1) / ROWS_PER_BLK;
    int nPartsMax = nPartsN > nPartsE ? nPartsN : nPartsE;

    float* ws  = (float*)d_ws;
    float* P   = ws;                       // [2][nParts][LDP] partials, reused per phase
    float* c1  = P + (size_t)2 * nPartsMax * LDP;
    float* d1  = c1 + Nn;
    float* c2  = d1 + Nn;
    float* d2  = c2 + Nn;
    float* ce1 = d2 + Nn;
    float* ce2 = ce1 + Ne;
    float* n1  = ce2 + Ne;     // [s(32), p(32), q(32)]
    float* n2  = n1 + 96;
    float* eg1 = n2 + 96;      // [s(16), p(16)]
    float* eg2 = eg1 + 32;
    float* scoring = eg2 + 32; // [4][16]
    // zero only the atomically-accumulated tail: n1..scoring = 320 floats
    hipMemsetAsync(n1, 0, 320 * sizeof(float), stream);

    dim3 blk(THREADS);
    dim3 gridN((Nn + THREADS * 4 - 1) / (THREADS * 4), nPartsN, 2);  // 6 x 94 x 2
    dim3 gridE((Ne + THREADS * 4 - 1) / (THREADS * 4), nPartsE, 2);
    dim3 gridRN((Nn + THREADS - 1) / THREADS, 2);                    // 24 x 2
    dim3 gridRE((Ne + THREADS - 1) / THREADS, 2);

    // Phase 1: unweighted colsums of adj1+adj2 (288 MB, one kernel)
    colsum2_kernel<false><<<gridN, blk, 0, stream>>>(adj1, adj2, nullptr, nullptr, P, Nn, nPartsN);
    reduce2_kernel<<<gridRN, blk, 0, stream>>>(P, c1, c2, Nn, nPartsN);
    // Phase 2: weighted colsums (re-read adj1+adj2; L3 holds most of it)
    colsum2_kernel<true ><<<gridN, blk, 0, stream>>>(adj1, adj2, c1, c2, P, Nn, nPartsN);
    reduce2_kernel<<<gridRN, blk, 0, stream>>>(P, d1, d2, Nn, nPartsN);
    // Phase 3: edge adjacency colsums (288 MB)
    colsum2_kernel<false><<<gridE, blk, 0, stream>>>(eadj1, eadj2, nullptr, nullptr, P, Ne, nPartsE);
    reduce2_kernel<<<gridRE, blk, 0, stream>>>(P, ce1, ce2, Ne, nPartsE);

    feat_all_kernel<<<dim3(16, 4), blk, 0, stream>>>(emb1, emb2, eat1, eat2,
                                                     c1, d1, c2, d2, ce1, ce2,
                                                     n1, n2, eg1, eg2, Nn, Ne);

    scoring_kernel<<<dim3(16, 4), blk, 0, stream>>>(Wn, We, n1, n2, eg1, eg2, scoring);

    final_kernel<<<1, 64, 0, stream>>>(scoring, n1, n2, eg1, eg2,
                                       Wbn, bn, Wbe, be,
                                       m1w, m1b, m2w, m2b, m3w, m3b, sw, sb,
                                       avg_v, (float*)d_out);
}

// Round 4
// 254.472 us; speedup vs baseline: 1.7530x; 1.0084x over previous
//
#include <hip/hip_runtime.h>
#include <cstdint>
#include <cmath>

#define THREADS 256
#define ROWS_PER_BLK 64
#define LDP 6016   // padded leading dim for partials (multiple of 4)

// Fused partial column sums for TWO matrices (blockIdx.z selects), NO atomics.
// P[z][blockIdx.y][col] = sum_{r in strip} (W ? w[r] : 1) * A[r][col]
// 16-deep explicit load batches for memory-level parallelism.
template <bool WEIGHTED>
__global__ void colsum2_kernel(const float* __restrict__ A0,
                               const float* __restrict__ A1,
                               const float* __restrict__ w0,
                               const float* __restrict__ w1,
                               float* __restrict__ P,
                               int N, int nParts) {
    const float* __restrict__ A = blockIdx.z ? A1 : A0;
    const float* __restrict__ w = blockIdx.z ? w1 : w0;
    float* Pm = P + (size_t)blockIdx.z * nParts * LDP;

    int col = blockIdx.x * (THREADS * 4) + threadIdx.x * 4;
    if (col >= N) return;
    int r0 = blockIdx.y * ROWS_PER_BLK;
    int r1 = r0 + ROWS_PER_BLK;
    if (r1 > N) r1 = N;

    float ax = 0.f, ay = 0.f, az = 0.f, aw = 0.f;
    float bx = 0.f, by = 0.f, bz = 0.f, bw = 0.f;   // second chain
    const float* p = A + (size_t)r0 * N + col;
    int r = r0;
    for (; r + 16 <= r1; r += 16) {
        float4 v[16];
#pragma unroll
        for (int i = 0; i < 16; ++i)
            v[i] = *reinterpret_cast<const float4*>(p + (size_t)i * N);
        float wv[16];
        if (WEIGHTED) {
#pragma unroll
            for (int i = 0; i < 16; ++i) wv[i] = w[r + i];
        }
#pragma unroll
        for (int i = 0; i < 16; i += 2) {
            float wa = WEIGHTED ? wv[i]     : 1.0f;
            float wb = WEIGHTED ? wv[i + 1] : 1.0f;
            ax += wa * v[i].x;     ay += wa * v[i].y;
            az += wa * v[i].z;     aw += wa * v[i].w;
            bx += wb * v[i + 1].x; by += wb * v[i + 1].y;
            bz += wb * v[i + 1].z; bw += wb * v[i + 1].w;
        }
        p += (size_t)16 * N;
    }
    for (; r < r1; ++r, p += N) {   // remainder (not hit for N=6000)
        float4 v = *reinterpret_cast<const float4*>(p);
        float wr = WEIGHTED ? w[r] : 1.0f;
        ax += wr * v.x; ay += wr * v.y; az += wr * v.z; aw += wr * v.w;
    }
    float4 o = {ax + bx, ay + by, az + bz, aw + bw};
    *reinterpret_cast<float4*>(&Pm[(size_t)blockIdx.y * LDP + col]) = o;
}

// Fused stage-2 for two outputs: out_z[col] = sum_i P[z][i][col].
__global__ void reduce2_kernel(const float* __restrict__ P,
                               float* __restrict__ out0,
                               float* __restrict__ out1,
                               int N, int nParts) {
    int col = blockIdx.x * THREADS + threadIdx.x;
    if (col >= N) return;
    const float* p = P + (size_t)blockIdx.y * nParts * LDP + col;
    float* out = blockIdx.y ? out1 : out0;
    float s = 0.f;
#pragma unroll 4
    for (int i = 0; i < nParts; ++i, p += LDP) s += *p;
    out[col] = s;
}

// Merged feature reductions for all 4 branches.
__global__ void feat_all_kernel(const float* __restrict__ emb1,
                                const float* __restrict__ emb2,
                                const float* __restrict__ eat1,
                                const float* __restrict__ eat2,
                                const float* __restrict__ c1,
                                const float* __restrict__ d1,
                                const float* __restrict__ c2,
                                const float* __restrict__ d2,
                                const float* __restrict__ ce1,
                                const float* __restrict__ ce2,
                                float* __restrict__ n1,
                                float* __restrict__ n2,
                                float* __restrict__ eg1,
                                float* __restrict__ eg2,
                                int Nn, int Ne) {
    int unit = blockIdx.y;
    const float *feat, *c, *d;
    float* out;
    int total, log2L;
    bool hasQ;
    if (unit == 0)      { feat = emb1; c = c1;  d = d1;      out = n1;  total = Nn * 32; log2L = 5; hasQ = true;  }
    else if (unit == 1) { feat = emb2; c = c2;  d = d2;      out = n2;  total = Nn * 32; log2L = 5; hasQ = true;  }
    else if (unit == 2) { feat = eat1; c = ce1; d = nullptr; out = eg1; total = Ne * 16; log2L = 4; hasQ = false; }
    else                { feat = eat2; c = ce2; d = nullptr; out = eg2; total = Ne * 16; log2L = 4; hasQ = false; }

    int stride = gridDim.x * blockDim.x;   // multiple of L
    int idx = blockIdx.x * blockDim.x + threadIdx.x;
    int L = 1 << log2L;
    int l = idx & (L - 1);
    float as = 0.f, ap = 0.f, aq = 0.f;
    for (int i = idx; i < total; i += stride) {
        float v = feat[i];
        int r = i >> log2L;
        as += v;
        ap += c[r] * v;
        if (hasQ) aq += d[r] * v;
    }
    atomicAdd(&out[l], as);
    atomicAdd(&out[L + l], ap);
    if (hasQ) atomicAdd(&out[2 * L + l], aq);
}

// scoring[b][k] = sum_{d,e} e1[d] * W[d,e,k] * e2[e]
__global__ void scoring_kernel(const float* __restrict__ Wn,
                               const float* __restrict__ We,
                               const float* __restrict__ n1,
                               const float* __restrict__ n2,
                               const float* __restrict__ eg1,
                               const float* __restrict__ eg2,
                               float* __restrict__ scoring) {
    int b = blockIdx.y;
    int chunk = blockIdx.x;
    const float *W, *e1, *e2;
    int total, log2D;
    if (b < 3) {
        W = Wn + (size_t)b * (64 * 64 * 16);
        e1 = n1 + (b == 2 ? 32 : 0);   // b0,b1: g_01 ; b2: g_12
        e2 = n2 + (b == 2 ? 32 : 0);
        total = 64 * 64 * 16;
        log2D = 6;
    } else {
        W = We;
        e1 = eg1;
        e2 = eg2;
        total = 32 * 32 * 16;
        log2D = 5;
    }
    int begin = chunk * 4096 + threadIdx.x;
    int end = (chunk + 1) * 4096;
    if (end > total) end = total;
    float acc = 0.f;
    for (int idx = begin; idx < end; idx += 256) {
        int de = idx >> 4;
        int e = de & ((1 << log2D) - 1);
        int dd = de >> log2D;
        acc += e1[dd] * e2[e] * W[idx];
    }
    __shared__ float red[256];
    red[threadIdx.x] = acc;
    __syncthreads();
    if (threadIdx.x < 16) {
        float s = 0.f;
        for (int t = threadIdx.x; t < 256; t += 16) s += red[t];
        atomicAdd(&scoring[b * 16 + threadIdx.x], s);
    }
}

// One block, 64 threads: block-term + relu -> MLPs -> sigmoid -> outputs.
__global__ void final_kernel(const float* __restrict__ scoring,
                             const float* __restrict__ n1,
                             const float* __restrict__ n2,
                             const float* __restrict__ eg1,
                             const float* __restrict__ eg2,
                             const float* __restrict__ Wbn,
                             const float* __restrict__ bn,
                             const float* __restrict__ Wbe,
                             const float* __restrict__ be,
                             const float* __restrict__ m1w,
                             const float* __restrict__ m1b,
                             const float* __restrict__ m2w,
                             const float* __restrict__ m2b,
                             const float* __restrict__ m3w,
                             const float* __restrict__ m3b,
                             const float* __restrict__ sw,
                             const float* __restrict__ sb,
                             const float* __restrict__ avg_v,
                             float* __restrict__ out) {
    __shared__ float sval[4][16];
    __shared__ float scores[4];
    int t = threadIdx.x;          // 64 threads
    int b = t >> 4, k = t & 15;

    float blk;
    if (b < 3) {
        const float* e1 = n1 + (b == 2 ? 32 : 0);
        const float* e2 = n2 + (b == 2 ? 32 : 0);
        const float* wb = Wbn + (size_t)b * (16 * 128) + k * 128;
        float s = 0.f;
        for (int j = 0; j < 64; ++j) s += wb[j] * e1[j];
        for (int j = 0; j < 64; ++j) s += wb[64 + j] * e2[j];
        blk = s + bn[b * 16 + k];
    } else {
        const float* wb = Wbe + k * 64;
        float s = 0.f;
        for (int j = 0; j < 32; ++j) s += wb[j] * eg1[j];
        for (int j = 0; j < 32; ++j) s += wb[32 + j] * eg2[j];
        blk = s + be[k];
    }
    float v = scoring[b * 16 + k] + blk;
    sval[b][k] = v > 0.f ? v : 0.f;
    __syncthreads();

    if (t < 4) {
        float h1[16], h2[8], h3[4];
        for (int o = 0; o < 16; ++o) {
            float a = m1b[t * 16 + o];
            for (int i = 0; i < 16; ++i) a += m1w[(t * 16 + o) * 16 + i] * sval[t][i];
            h1[o] = a > 0.f ? a : 0.f;
        }
        for (int o = 0; o < 8; ++o) {
            float a = m2b[t * 8 + o];
            for (int i = 0; i < 16; ++i) a += m2w[(t * 8 + o) * 16 + i] * h1[i];
            h2[o] = a > 0.f ? a : 0.f;
        }
        for (int o = 0; o < 4; ++o) {
            float a = m3b[t * 4 + o];
            for (int i = 0; i < 8; ++i) a += m3w[(t * 4 + o) * 8 + i] * h2[i];
            h3[o] = a > 0.f ? a : 0.f;
        }
        float z = sb[t];
        for (int i = 0; i < 4; ++i) z += sw[t * 4 + i] * h3[i];
        scores[t] = 1.0f / (1.0f + expf(-z));
    }
    __syncthreads();

    if (t == 0) {
        const int ord[4] = {0, 1, 3, 2};   // (nc, in, ec, ie)
        float av = avg_v[0];
        float acc = 0.f;
        for (int j = 0; j < 4; ++j) {
            float sc = scores[ord[j]];
            out[2 + j] = sc;
            acc += -logf(sc);
        }
        float ged = acc * av;
        out[1] = ged;
        out[0] = expf(-ged / av);
    }
}

extern "C" void kernel_launch(void* const* d_in, const int* in_sizes, int n_in,
                              void* d_out, int out_size, void* d_ws, size_t ws_size,
                              hipStream_t stream) {
    const float* emb1  = (const float*)d_in[0];
    const float* emb2  = (const float*)d_in[1];
    const float* adj1  = (const float*)d_in[2];
    const float* adj2  = (const float*)d_in[3];
    const float* eat1  = (const float*)d_in[4];
    const float* eat2  = (const float*)d_in[5];
    const float* eadj1 = (const float*)d_in[6];
    const float* eadj2 = (const float*)d_in[7];
    const float* avg_v = (const float*)d_in[8];
    const float* Wn    = (const float*)d_in[9];
    const float* Wbn   = (const float*)d_in[10];
    const float* bn    = (const float*)d_in[11];
    const float* We    = (const float*)d_in[12];
    const float* Wbe   = (const float*)d_in[13];
    const float* be    = (const float*)d_in[14];
    const float* m1w   = (const float*)d_in[15];
    const float* m1b   = (const float*)d_in[16];
    const float* m2w   = (const float*)d_in[17];
    const float* m2b   = (const float*)d_in[18];
    const float* m3w   = (const float*)d_in[19];
    const float* m3b   = (const float*)d_in[20];
    const float* sw    = (const float*)d_in[21];
    const float* sb    = (const float*)d_in[22];

    int Nn = in_sizes[0] / 32;   // 6000 nodes
    int Ne = in_sizes[4] / 16;   // 6000 edges
    int nPartsN = (Nn + ROWS_PER_BLK - 1) / ROWS_PER_BLK;   // 94
    int nPartsE = (Ne + ROWS_PER_BLK - 1) / ROWS_PER_BLK;
    int nPartsMax = nPartsN > nPartsE ? nPartsN : nPartsE;

    float* ws  = (float*)d_ws;
    float* P   = ws;                       // [2][nParts][LDP] partials, reused per phase
    float* c1  = P + (size_t)2 * nPartsMax * LDP;
    float* d1  = c1 + Nn;
    float* c2  = d1 + Nn;
    float* d2  = c2 + Nn;
    float* ce1 = d2 + Nn;
    float* ce2 = ce1 + Ne;
    float* n1  = ce2 + Ne;     // [s(32), p(32), q(32)]
    float* n2  = n1 + 96;
    float* eg1 = n2 + 96;      // [s(16), p(16)]
    float* eg2 = eg1 + 32;
    float* scoring = eg2 + 32; // [4][16]
    // zero only the atomically-accumulated tail: n1..scoring = 320 floats
    hipMemsetAsync(n1, 0, 320 * sizeof(float), stream);

    dim3 blk(THREADS);
    dim3 gridN((Nn + THREADS * 4 - 1) / (THREADS * 4), nPartsN, 2);  // 6 x 94 x 2
    dim3 gridE((Ne + THREADS * 4 - 1) / (THREADS * 4), nPartsE, 2);
    dim3 gridRN((Nn + THREADS - 1) / THREADS, 2);                    // 24 x 2
    dim3 gridRE((Ne + THREADS - 1) / THREADS, 2);

    // Phase 1: unweighted colsums of adj1+adj2 (288 MB, one kernel)
    colsum2_kernel<false><<<gridN, blk, 0, stream>>>(adj1, adj2, nullptr, nullptr, P, Nn, nPartsN);
    reduce2_kernel<<<gridRN, blk, 0, stream>>>(P, c1, c2, Nn, nPartsN);
    // Phase 2: weighted colsums (re-read adj1+adj2)
    colsum2_kernel<true ><<<gridN, blk, 0, stream>>>(adj1, adj2, c1, c2, P, Nn, nPartsN);
    reduce2_kernel<<<gridRN, blk, 0, stream>>>(P, d1, d2, Nn, nPartsN);
    // Phase 3: edge adjacency colsums (288 MB)
    colsum2_kernel<false><<<gridE, blk, 0, stream>>>(eadj1, eadj2, nullptr, nullptr, P, Ne, nPartsE);
    reduce2_kernel<<<gridRE, blk, 0, stream>>>(P, ce1, ce2, Ne, nPartsE);

    feat_all_kernel<<<dim3(16, 4), blk, 0, stream>>>(emb1, emb2, eat1, eat2,
                                                     c1, d1, c2, d2, ce1, ce2,
                                                     n1, n2, eg1, eg2, Nn, Ne);

    scoring_kernel<<<dim3(16, 4), blk, 0, stream>>>(Wn, We, n1, n2, eg1, eg2, scoring);

    final_kernel<<<1, 64, 0, stream>>>(scoring, n1, n2, eg1, eg2,
                                       Wbn, bn, Wbe, be,
                                       m1w, m1b, m2w, m2b, m3w, m3b, sw, sb,
                                       avg_v, (float*)d_out);
}